// Round 5
// baseline (300.811 us; speedup 1.0000x reference)
//
#include <hip/hip_runtime.h>
#include <math.h>

// ---------------- problem constants ----------------
constexpr int N_    = 10000;
constexpr int E_    = 320000;
constexpr int IND   = 128;
constexpr int HID   = 32;
constexpr int OUTD  = 128;
constexpr int NIV   = 33;      // max intervals = 32 breakpoints + 1
constexpr float EPS = 1e-5f;

// ---------------- workspace layout (element offsets, 4B each) ----
constexpr size_t OFF_SUMH   = 0;       // 128 f
constexpr size_t OFF_SQH    = 128;     // 128 f
constexpr size_t OFF_SUMP   = 256;     // 32 f
constexpr size_t OFF_SQP    = 288;     // 32 f
constexpr size_t OFF_SUMU   = 320;     // 32 f
constexpr size_t OFF_SQU    = 352;     // 32 f
constexpr size_t OFF_SUMO   = 384;     // 128 f
constexpr size_t OFF_SQO    = 512;     // 128 f
constexpr size_t OFF_OCC    = 640;     // 33 i
constexpr size_t OFF_DEGIN  = 704;     // 10000 i
constexpr size_t OFF_DEGOUT = 10704;   // 10000 i
constexpr size_t ZERO_CNT   = 20704;   // elements zeroed by memset
constexpr size_t OFF_STARTS = 20740;   // 10001 i  CSR row starts
constexpr size_t OFF_CUR    = 30744;   // 10000 i  scatter cursors
constexpr size_t OFF_C1     = 40744;   // 33*1056 f
constexpr size_t OFF_C0     = 75592;   // 33*1056 f
constexpr size_t OFF_P      = 110440;  // N*32 f (16B aligned)
constexpr size_t OFF_UPD    = 430440;  // N*32 f
constexpr size_t OFF_AEN    = 750440;  // E float2 records {a, nin|(iv<<16)} in CSR order
// total 750440 + 640000 = 1390440 elems = 5.56 MB

// helper: sorted breakpoints of relu(a*kw1+kb1) — recomputed locally wherever
// needed (NO cross-block data dependence).
__device__ inline int compute_bps(const float* kw1, const float* kb1, float* bp) {
    int m = 0;
    for (int k = 0; k < 32; ++k) {
        float w = kw1[k];
        if (w != 0.f) bp[m++] = -kb1[k] / w;
    }
    for (int a = 1; a < m; ++a) {
        float v = bp[a]; int b = a - 1;
        while (b >= 0 && bp[b] > v) { bp[b+1] = bp[b]; --b; }
        bp[b+1] = v;
    }
    return m;
}

// =======================================================================
// K_A (fused): blocks [0,33) interval tables | [33,161) H stats |
//              [161,474) per-edge interval occupancy + in/out degree
// =======================================================================
__global__ __launch_bounds__(256)
void k_A(const float* __restrict__ H,
         const float* __restrict__ ea, const int* __restrict__ edges,
         const float* __restrict__ kw1, const float* __restrict__ kb1,
         const float* __restrict__ kw2, const float* __restrict__ kb2,
         float* __restrict__ ws) {
    __shared__ float sel1[32], sel0[32];
    __shared__ float shS[256], shQ[256];
    __shared__ int locc[NIV];
    __shared__ float bps[32];
    int* wsi = (int*)ws;
    int t = threadIdx.x;
    int bid = blockIdx.x;

    if (bid < 33) {
        // ---- interval tables ----
        int i = bid;
        if (t == 0) {
            float bp[32];
            int m = compute_bps(kw1, kb1, bp);
            float arep;
            if (m == 0 || i > m) arep = 0.f;
            else if (i == 0)     arep = bp[0]   - (1.f + 0.5f*fabsf(bp[0]));
            else if (i == m)     arep = bp[m-1] + (1.f + 0.5f*fabsf(bp[m-1]));
            else                 arep = (bp[i-1] < bp[i]) ? 0.5f*(bp[i-1] + bp[i]) : bp[i-1];
            for (int k = 0; k < 32; ++k) {
                bool s = (arep * kw1[k] + kb1[k]) > 0.f;
                sel1[k] = s ? kw1[k] : 0.f;
                sel0[k] = s ? kb1[k] : 0.f;
            }
        }
        __syncthreads();
        for (int r = t; r < 1056; r += 256) {
            float a1 = 0.f, a0 = 0.f;
            for (int k = 0; k < 32; ++k) {
                float w = kw2[r*32 + k];
                a1 += w * sel1[k];
                a0 += w * sel0[k];
            }
            ws[OFF_C1 + (size_t)i*1056 + r] = a1;
            ws[OFF_C0 + (size_t)i*1056 + r] = a0 + kb2[r];
        }
    } else if (bid < 161) {
        // ---- column stats of H ----
        int b2 = bid - 33;
        int col = t & 127, half = t >> 7;
        float s = 0.f, q = 0.f;
        for (int r = b2*2 + half; r < N_; r += 128*2) {
            float x = H[(size_t)r*IND + col];
            s += x; q += x*x;
        }
        shS[t] = s; shQ[t] = q;
        __syncthreads();
        if (t < 128) {
            atomicAdd(&ws[OFF_SUMH + t], shS[t] + shS[t+128]);
            atomicAdd(&ws[OFF_SQH  + t], shQ[t] + shQ[t+128]);
        }
    } else {
        // ---- per-edge interval occupancy + degrees ----
        int b2 = bid - 161;
        if (t < NIV) locc[t] = 0;
        if (t == 0) {
            float bp[32];
            int m = compute_bps(kw1, kb1, bp);
            for (int k = 0; k < 32; ++k) bps[k] = (k < m) ? bp[k] : 3.0e38f;
        }
        __syncthreads();
        for (int e = b2*256 + t; e < E_; e += 313*256) {
            float a = ea[e];
            int cnt = 0;
            #pragma unroll
            for (int k = 0; k < 32; ++k) cnt += (bps[k] < a) ? 1 : 0;
            atomicAdd(&locc[cnt], 1);
            atomicAdd(&wsi[OFF_DEGIN  + edges[E_ + e]], 1);
            atomicAdd(&wsi[OFF_DEGOUT + edges[e]],      1);
        }
        __syncthreads();
        if (t < NIV && locc[t] > 0) atomicAdd(&wsi[OFF_OCC + t], locc[t]);
    }
}

// =======================================================================
// K_B (fused): block 0 = exclusive scan of out-degree -> starts/cur
//              blocks 1..1250 = P = relu(bn_in(H)) @ w1.T + b1
// =======================================================================
__global__ __launch_bounds__(256)
void k_B(const float* __restrict__ H, const float* __restrict__ w1,
         const float* __restrict__ b1, const float* __restrict__ g_in,
         const float* __restrict__ beta_in, float* __restrict__ ws) {
    __shared__ float w1L[32*129];
    __shared__ float xl[8][128];
    __shared__ int part[256];
    int* wsi = (int*)ws;
    int t = threadIdx.x;

    if (blockIdx.x == 0) {
        // ---- exclusive scan of DEGOUT over 10001 entries ----
        int base = t * 40;
        int loc[40];
        int s = 0;
        for (int i = 0; i < 40; ++i) {
            int idx = base + i;
            int v = (idx < N_) ? wsi[OFF_DEGOUT + idx] : 0;
            loc[i] = s; s += v;
        }
        part[t] = s;
        __syncthreads();
        for (int off = 1; off < 256; off <<= 1) {
            int add = (t >= off) ? part[t - off] : 0;
            __syncthreads();
            part[t] += add;
            __syncthreads();
        }
        int pre = (t > 0) ? part[t-1] : 0;
        for (int i = 0; i < 40; ++i) {
            int idx = base + i;
            if (idx <= N_) {
                int v = pre + loc[i];
                wsi[OFF_STARTS + idx] = v;
                if (idx < N_) wsi[OFF_CUR + idx] = v;
            }
        }
        return;
    }

    // ---- nodeP: 8 nodes per block, 32 threads per node ----
    int g = t >> 5, j = t & 31;
    for (int idx = t; idx < 4096; idx += 256)
        w1L[(idx >> 7)*129 + (idx & 127)] = w1[idx];

    int n = (blockIdx.x - 1)*8 + g;
    float4 h4 = ((const float4*)(H + (size_t)n*IND))[j];
    float4 m4 = ((const float4*)(ws + OFF_SUMH))[j];
    float4 q4 = ((const float4*)(ws + OFF_SQH))[j];
    float4 gg = ((const float4*)g_in)[j];
    float4 bb = ((const float4*)beta_in)[j];
    float4 xv;
    {
        float* hp = (float*)&h4; float* mp = (float*)&m4; float* qp = (float*)&q4;
        float* gp = (float*)&gg; float* bp = (float*)&bb; float* xp = (float*)&xv;
        for (int i = 0; i < 4; ++i) {
            float mean = mp[i] * (1.f/N_);
            float var  = qp[i] * (1.f/N_) - mean*mean;
            float istd = 1.f / sqrtf(var + EPS);
            float gc = gp[i]*istd, bc = bp[i] - mean*gc;
            xp[i] = fmaxf(fmaf(gc, hp[i], bc), 0.f);
        }
    }
    ((float4*)&xl[g][0])[j] = xv;
    __syncthreads();
    float p = b1[j];
    const float* wr = &w1L[j*129];
    const float* xr = &xl[g][0];
    #pragma unroll 8
    for (int k = 0; k < 128; ++k) p = fmaf(wr[k], xr[k], p);
    ws[OFF_P + (size_t)n*HID + j] = p;
}

// =======================================================================
// K_C (fused): blocks [0,313) build CSR-ordered edge records {a, nin|iv<<16} |
//              [313,377) degree-weighted stats of P (= msg stats over E)
// =======================================================================
__global__ __launch_bounds__(256)
void k_C(const float* __restrict__ ea, const int* __restrict__ edges,
         const float* __restrict__ kw1, const float* __restrict__ kb1,
         float* __restrict__ ws) {
    __shared__ float shS[256], shQ[256];
    __shared__ float bps[32];
    int* wsi = (int*)ws;
    int t = threadIdx.x;
    if (blockIdx.x < 313) {
        if (t == 0) {
            float bp[32];
            int m = compute_bps(kw1, kb1, bp);
            for (int k = 0; k < 32; ++k) bps[k] = (k < m) ? bp[k] : 3.0e38f;
        }
        __syncthreads();
        float2* aen = (float2*)(ws + OFF_AEN);
        int b2 = blockIdx.x;
        for (int e = b2*256 + t; e < E_; e += 313*256) {
            int   nout = edges[e];
            int   nin  = edges[E_ + e];
            float a    = ea[e];
            int iv = 0;
            #pragma unroll
            for (int k = 0; k < 32; ++k) iv += (bps[k] < a) ? 1 : 0;
            int pos = atomicAdd(&wsi[OFF_CUR + nout], 1);
            float2 rec; rec.x = a; rec.y = __int_as_float(nin | (iv << 16));
            aen[pos] = rec;
        }
    } else {
        int b2 = blockIdx.x - 313;
        int j = t & 31, cp = t >> 5;
        float s = 0.f, q = 0.f;
        for (int n = b2*8 + cp; n < N_; n += 64*8) {
            float w = (float)wsi[OFF_DEGIN + n];
            float p = ws[OFF_P + (size_t)n*HID + j];
            s += w*p; q += w*p*p;
        }
        shS[t] = s; shQ[t] = q;
        __syncthreads();
        if (t < 32) {
            float S = 0.f, Qq = 0.f;
            for (int c = 0; c < 8; ++c) { S += shS[t + 32*c]; Qq += shQ[t + 32*c]; }
            atomicAdd(&ws[OFF_SUMP + t], S);
            atomicAdd(&ws[OFF_SQP  + t], Qq);
        }
    }
}

// =======================================================================
// K_D: segment reduce, wave-per-node.
//   All 64 lanes of a wave process ONE node's edge list together. Record
//   loads are same-address across the wave (single L2 fetch, broadcast in
//   registers — NO shfl/bpermute in the hot loop). Lanes j and j+32
//   redundantly compute column j&31 (identical accumulators; no combine).
//   8-deep unroll + double-buffered record prefetch for MLP.
// =======================================================================
__global__ __launch_bounds__(256)
void k_D(const float* __restrict__ g_msg, const float* __restrict__ beta_msg,
         float* __restrict__ ws) {
    __shared__ float A[4][32*33];   // A1_s0, A0_s0, A1_s1, A0_s1 (padded rows)
    __shared__ float Bv[4][32];     // bias rows
    __shared__ float zx[4][4][32];  // per-wave z exchange
    __shared__ float fb[4][32];     // fallback q exchange (correctness path)
    __shared__ float shS[256], shQ[256];
    __shared__ int s_slot0, s_slot1;
    int* wsi = (int*)ws;
    int t = threadIdx.x;
    int w = t >> 6;        // wave 0..3
    int lane = t & 63;
    int j = lane & 31;     // column

    if (t == 0) {
        int a0 = -1, a1 = -1;
        for (int i = 0; i < NIV; ++i)
            if (wsi[OFF_OCC + i] > 0) { if (a0 < 0) a0 = i; else if (a1 < 0) a1 = i; }
        s_slot0 = a0; s_slot1 = a1;
    }
    __syncthreads();
    int s0 = s_slot0, s1 = s_slot1;

    for (int idx = t; idx < 1024; idx += 256) {
        int jj = idx >> 5, kk = idx & 31;
        A[0][jj*33+kk] = (s0 >= 0) ? ws[OFF_C1 + (size_t)s0*1056 + 32 + idx] : 0.f;
        A[1][jj*33+kk] = (s0 >= 0) ? ws[OFF_C0 + (size_t)s0*1056 + 32 + idx] : 0.f;
        A[2][jj*33+kk] = (s1 >= 0) ? ws[OFF_C1 + (size_t)s1*1056 + 32 + idx] : 0.f;
        A[3][jj*33+kk] = (s1 >= 0) ? ws[OFF_C0 + (size_t)s1*1056 + 32 + idx] : 0.f;
    }
    if (t < 32) {
        Bv[0][t] = (s0 >= 0) ? ws[OFF_C1 + (size_t)s0*1056 + t] : 0.f;
        Bv[1][t] = (s0 >= 0) ? ws[OFF_C0 + (size_t)s0*1056 + t] : 0.f;
        Bv[2][t] = (s1 >= 0) ? ws[OFF_C1 + (size_t)s1*1056 + t] : 0.f;
        Bv[3][t] = (s1 >= 0) ? ws[OFF_C0 + (size_t)s1*1056 + t] : 0.f;
    }
    // bn_msg constants for column j
    float mP = ws[OFF_SUMP + j] * (1.f/E_);
    float vP = ws[OFF_SQP  + j] * (1.f/E_) - mP*mP;
    float istd = 1.f / sqrtf(vP + EPS);
    float gc = g_msg[j]*istd, bc = beta_msg[j] - mP*gc;
    __syncthreads();

    int n = blockIdx.x*4 + w;
    int st = wsi[OFF_STARTS + n], en = wsi[OFF_STARTS + n + 1];
    float za0 = 0.f, zb0 = 0.f, za1 = 0.f, zb1 = 0.f;
    float suma0 = 0.f, suma1 = 0.f, c0f = 0.f, c1f = 0.f, rfall = 0.f;
    const float2* aen = (const float2*)(ws + OFF_AEN);

    if (st < en) {
        float2 rcur[8], rnext[8];
        #pragma unroll
        for (int q = 0; q < 8; ++q) {
            int idx = st + q; if (idx >= en) idx = en - 1;
            rcur[q] = aen[idx];
        }
        for (int base = st; base < en; base += 8) {
            int nb = base + 8;
            if (nb < en) {
                #pragma unroll
                for (int q = 0; q < 8; ++q) {
                    int idx = nb + q; if (idx >= en) idx = en - 1;
                    rnext[q] = aen[idx];
                }
            }
            #pragma unroll
            for (int q = 0; q < 8; ++q) {
                bool valid = (base + q) < en;
                float a = rcur[q].x;
                int  mt = __float_as_int(rcur[q].y);
                int nin = mt & 0xFFFF, iv = mt >> 16;
                float pv = ws[OFF_P + (size_t)nin*HID + j];
                float qv = fmaxf(fmaf(gc, pv, bc), 0.f);
                if (__builtin_expect(valid && iv != s0 && iv != s1, 0)) {
                    // general fallback (not taken with given inputs)
                    if (lane < 32) fb[w][j] = qv;
                    const float* C1r = ws + OFF_C1 + (size_t)iv*1056;
                    const float* C0r = ws + OFF_C0 + (size_t)iv*1056;
                    float d1 = 0.f, d0 = 0.f;
                    for (int k2 = 0; k2 < 32; ++k2) {
                        float qk = fb[w][k2];
                        d1 += C1r[32 + j*32 + k2] * qk;
                        d0 += C0r[32 + j*32 + k2] * qk;
                    }
                    rfall += a*(d1 + C1r[j]) + (d0 + C0r[j]);
                } else {
                    float w0 = (valid && iv == s0) ? 1.f : 0.f;
                    float w1 = (valid && iv == s1) ? 1.f : 0.f;
                    float w0a = w0 * a, w1a = w1 * a;
                    za0 = fmaf(w0a, qv, za0); zb0 = fmaf(w0, qv, zb0);
                    za1 = fmaf(w1a, qv, za1); zb1 = fmaf(w1, qv, zb1);
                    suma0 += w0a; c0f += w0;
                    suma1 += w1a; c1f += w1;
                }
            }
            #pragma unroll
            for (int q = 0; q < 8; ++q) rcur[q] = rnext[q];
        }
    }

    if (lane < 32) {
        zx[w][0][j] = za0; zx[w][1][j] = zb0; zx[w][2][j] = za1; zx[w][3][j] = zb1;
    }
    __syncthreads();

    float acc = rfall;
    if (s0 >= 0) acc += suma0*Bv[0][j] + c0f*Bv[1][j];
    if (s1 >= 0) acc += suma1*Bv[2][j] + c1f*Bv[3][j];
    const float* z0 = zx[w][0]; const float* z1 = zx[w][1];
    const float* z2 = zx[w][2]; const float* z3 = zx[w][3];
    #pragma unroll 4
    for (int k = 0; k < 32; ++k) {
        acc += A[0][j*33+k]*z0[k] + A[1][j*33+k]*z1[k]
             + A[2][j*33+k]*z2[k] + A[3][j*33+k]*z3[k];
    }
    if (lane < 32) ws[OFF_UPD + (size_t)n*HID + j] = acc;

    // fused upd stats (zero out duplicate upper half-wave)
    shS[t] = (lane < 32) ? acc : 0.f;
    shQ[t] = (lane < 32) ? acc*acc : 0.f;
    __syncthreads();
    if (t < 32) {
        float S = 0.f, Qq = 0.f;
        for (int c = 0; c < 8; ++c) { S += shS[t + 32*c]; Qq += shQ[t + 32*c]; }
        atomicAdd(&ws[OFF_SUMU + t], S);
        atomicAdd(&ws[OFF_SQU  + t], Qq);
    }
}

// =======================================================================
// K_F: out_pre = relu(bn(upd)) @ w2.T + b2 ; accumulate out stats
// =======================================================================
__global__ __launch_bounds__(256)
void k_F(const float* __restrict__ w2, const float* __restrict__ b2,
         const float* __restrict__ g_upd, const float* __restrict__ beta_upd,
         float* __restrict__ ws, float* __restrict__ out) {
    __shared__ float U[2][HID];
    __shared__ float shS[256], shQ[256];
    int t = threadIdx.x, nh = t >> 7, o = t & 127;
    float gc = 0.f, bc = 0.f;
    if (o < 32) {
        float m = ws[OFF_SUMU + o]*(1.f/N_);
        float v = ws[OFF_SQU  + o]*(1.f/N_) - m*m;
        float istd = 1.f/sqrtf(v + EPS);
        gc = g_upd[o]*istd; bc = beta_upd[o] - m*gc;
    }
    float w2r[32];
    for (int k = 0; k < 32; ++k) w2r[k] = w2[o*32 + k];
    float bo = b2[o];
    float sO = 0.f, qO = 0.f;
    for (int base = blockIdx.x*2; base < N_; base += gridDim.x*2) {
        int n = base + nh;
        if (o < 32) {
            float u = ws[OFF_UPD + (size_t)n*HID + o];
            U[nh][o] = fmaxf(fmaf(gc, u, bc), 0.f);
        }
        __syncthreads();
        float v = bo;
        for (int k = 0; k < 32; ++k) v = fmaf(w2r[k], U[nh][k], v);
        out[(size_t)n*OUTD + o] = v;
        sO += v; qO += v*v;
        __syncthreads();
    }
    shS[t] = sO; shQ[t] = qO;
    __syncthreads();
    if (t < 128) {
        atomicAdd(&ws[OFF_SUMO + t], shS[t] + shS[t+128]);
        atomicAdd(&ws[OFF_SQO  + t], shQ[t] + shQ[t+128]);
    }
}

// =======================================================================
// K_G: final output batch-norm (in-place)
// =======================================================================
__global__ __launch_bounds__(256)
void k_G(const float* __restrict__ g_out, const float* __restrict__ beta_out,
         const float* __restrict__ ws, float* __restrict__ out) {
    int g = blockIdx.x*blockDim.x + threadIdx.x;
    if (g >= N_*OUTD) return;
    int o = g & 127;
    float m = ws[OFF_SUMO + o]*(1.f/N_);
    float v = ws[OFF_SQO  + o]*(1.f/N_) - m*m;
    float istd = 1.f/sqrtf(v + EPS);
    out[g] = g_out[o]*istd*(out[g] - m) + beta_out[o];
}

// ---------------- launch -----------------------------------------------------
extern "C" void kernel_launch(void* const* d_in, const int* in_sizes, int n_in,
                              void* d_out, int out_size, void* d_ws, size_t ws_size,
                              hipStream_t stream) {
    const float* H        = (const float*)d_in[0];
    const float* ea       = (const float*)d_in[1];
    const int*   edges    = (const int*)  d_in[2];
    const float* w1       = (const float*)d_in[3];
    const float* b1       = (const float*)d_in[4];
    const float* kw1      = (const float*)d_in[5];
    const float* kb1      = (const float*)d_in[6];
    const float* kw2      = (const float*)d_in[7];
    const float* kb2      = (const float*)d_in[8];
    const float* w2       = (const float*)d_in[9];
    const float* b2       = (const float*)d_in[10];
    const float* g_in     = (const float*)d_in[11];
    const float* beta_in  = (const float*)d_in[12];
    const float* g_msg    = (const float*)d_in[13];
    const float* beta_msg = (const float*)d_in[14];
    const float* g_upd    = (const float*)d_in[15];
    const float* beta_upd = (const float*)d_in[16];
    const float* g_out    = (const float*)d_in[17];
    const float* beta_out = (const float*)d_in[18];
    float* ws  = (float*)d_ws;
    float* out = (float*)d_out;

    hipMemsetAsync(d_ws, 0, ZERO_CNT*sizeof(float), stream);
    hipLaunchKernelGGL(k_A, dim3(474),  dim3(256), 0, stream, H, ea, edges, kw1, kb1, kw2, kb2, ws);
    hipLaunchKernelGGL(k_B, dim3(1251), dim3(256), 0, stream, H, w1, b1, g_in, beta_in, ws);
    hipLaunchKernelGGL(k_C, dim3(377),  dim3(256), 0, stream, ea, edges, kw1, kb1, ws);
    hipLaunchKernelGGL(k_D, dim3(2500), dim3(256), 0, stream, g_msg, beta_msg, ws);
    hipLaunchKernelGGL(k_F, dim3(250),  dim3(256), 0, stream, w2, b2, g_upd, beta_upd, ws, out);
    hipLaunchKernelGGL(k_G, dim3((N_*OUTD + 255)/256), dim3(256), 0, stream, g_out, beta_out, ws, out);
}